// Round 3
// baseline (1882.828 us; speedup 1.0000x reference)
//
#include <hip/hip_runtime.h>
#include <cstdint>
#include <cstddef>

#define TOKENS 8192
#define HDIM 4096
#define ODIM 4096
#define NEXP 8

using short8  = __attribute__((ext_vector_type(8))) short;
using floatx4 = __attribute__((ext_vector_type(4))) float;

// fp32 -> bf16 with round-to-nearest-even
__device__ __forceinline__ unsigned short f2bf(float f) {
  unsigned u = __float_as_uint(f);
  u = u + 0x7fffu + ((u >> 16) & 1u);
  return (unsigned short)(u >> 16);
}

// async global->LDS, 16B per lane; LDS dest = wave-uniform base + lane*16
__device__ __forceinline__ void async_ld16(const void* g, void* l) {
  __builtin_amdgcn_global_load_lds((const __attribute__((address_space(1))) void*)g,
                                   (__attribute__((address_space(3))) void*)l,
                                   16, 0, 0);
}

// ---------------------------------------------------------------------------
// Kernel 1: gating (fp64 logits -> top-2 -> softmax) + x fp32->bf16.
// Slot scheme: sid = 2*token + k (k=0 top expert, k=1 second expert).
// ---------------------------------------------------------------------------
__global__ __launch_bounds__(256) void gate_kernel(
    const float* __restrict__ x, const float* __restrict__ gw,
    unsigned short* __restrict__ xb, int* __restrict__ counts,
    int* __restrict__ lists, float* __restrict__ wts)
{
  const int b = blockIdx.x;
  const int t = threadIdx.x;
  const float4* xr = (const float4*)(x + (size_t)b * HDIM);

  double acc[NEXP];
#pragma unroll
  for (int e = 0; e < NEXP; ++e) acc[e] = 0.0;

#pragma unroll
  for (int i = 0; i < 4; ++i) {
    const int idx = i * 256 + t;
    const float4 v = xr[idx];
    ushort4 pack = make_ushort4(f2bf(v.x), f2bf(v.y), f2bf(v.z), f2bf(v.w));
    *(ushort4*)(xb + (size_t)b * HDIM + (size_t)idx * 4) = pack;
    const float* g = gw + (size_t)idx * 4 * NEXP;
    const float xs[4] = {v.x, v.y, v.z, v.w};
#pragma unroll
    for (int j = 0; j < 4; ++j) {
      const float4 g0 = *(const float4*)(g + j * NEXP);
      const float4 g1 = *(const float4*)(g + j * NEXP + 4);
      const double xv = (double)xs[j];
      acc[0] += xv * (double)g0.x; acc[1] += xv * (double)g0.y;
      acc[2] += xv * (double)g0.z; acc[3] += xv * (double)g0.w;
      acc[4] += xv * (double)g1.x; acc[5] += xv * (double)g1.y;
      acc[6] += xv * (double)g1.z; acc[7] += xv * (double)g1.w;
    }
  }

#pragma unroll
  for (int off = 32; off > 0; off >>= 1)
#pragma unroll
    for (int e = 0; e < NEXP; ++e)
      acc[e] += __shfl_down(acc[e], off);

  __shared__ double sred[4][NEXP];
  const int w = t >> 6, lane = t & 63;
  if (lane == 0)
#pragma unroll
    for (int e = 0; e < NEXP; ++e) sred[w][e] = acc[e];
  __syncthreads();

  if (t == 0) {
    double lg[NEXP];
#pragma unroll
    for (int e = 0; e < NEXP; ++e)
      lg[e] = sred[0][e] + sred[1][e] + sred[2][e] + sred[3][e];
    int i0 = 0; double v0 = lg[0];
    for (int e = 1; e < NEXP; ++e) if (lg[e] > v0) { v0 = lg[e]; i0 = e; }
    int i1 = -1; double v1 = -1e300;
    for (int e = 0; e < NEXP; ++e) if (e != i0 && lg[e] > v1) { v1 = lg[e]; i1 = e; }
    const double d = exp(v1 - v0);
    const float w0 = (float)(1.0 / (1.0 + d));
    const float w1 = (float)(d / (1.0 + d));
    wts[2 * b]     = w0;
    wts[2 * b + 1] = w1;
    int p0 = atomicAdd(&counts[i0], 1);
    lists[i0 * TOKENS + p0] = 2 * b;
    int p1 = atomicAdd(&counts[i1], 1);
    lists[i1 * TOKENS + p1] = 2 * b + 1;
  }
}

// ---------------------------------------------------------------------------
// Kernel 2: expert_w fp32 [E,H,O] -> bf16 transposed [E,O,H]  (B^T for MFMA)
// ---------------------------------------------------------------------------
__global__ __launch_bounds__(256) void wt_kernel(
    const float* __restrict__ W, unsigned short* __restrict__ wt)
{
  const int e  = blockIdx.z;
  const int h0 = blockIdx.y * 64;
  const int o0 = blockIdx.x * 64;
  const int t  = threadIdx.x;
  __shared__ unsigned T[64 * 33];

  const float* Wb = W + (size_t)e * HDIM * ODIM;
  const int rp = t >> 4;       // 0..15  (h-pair)
  const int cq = t & 15;       // o-quad
#pragma unroll
  for (int p = 0; p < 2; ++p) {
    const int h = 2 * rp + 32 * p;
    const float4 v0 = *(const float4*)(Wb + (size_t)(h0 + h) * ODIM + o0 + 4 * cq);
    const float4 v1 = *(const float4*)(Wb + (size_t)(h0 + h + 1) * ODIM + o0 + 4 * cq);
    const float a0[4] = {v0.x, v0.y, v0.z, v0.w};
    const float a1[4] = {v1.x, v1.y, v1.z, v1.w};
#pragma unroll
    for (int j = 0; j < 4; ++j) {
      unsigned d = (unsigned)f2bf(a0[j]) | ((unsigned)f2bf(a1[j]) << 16);
      T[(4 * cq + j) * 33 + (h >> 1)] = d;
    }
  }
  __syncthreads();

#pragma unroll
  for (int p = 0; p < 2; ++p) {
    const int o_l = p * 32 + (t >> 3);
    const int dw  = (t & 7) * 4;
    const unsigned d0 = T[o_l * 33 + dw];
    const unsigned d1 = T[o_l * 33 + dw + 1];
    const unsigned d2 = T[o_l * 33 + dw + 2];
    const unsigned d3 = T[o_l * 33 + dw + 3];
    uint4 pack = make_uint4(d0, d1, d2, d3);
    *(uint4*)(wt + ((size_t)e * ODIM + o0 + o_l) * HDIM + h0 + dw * 2) = pack;
  }
}

// ---------------------------------------------------------------------------
// Kernel 3: grouped gather-GEMM, XOR-swizzled LDS, 2-phase double-buffered
// pipeline: STAGE(tile t+1) issued BEFORE compute(tile t); one barrier/tile
// so the vmcnt(0) drain at __syncthreads happens after loads had the whole
// MFMA phase to land (T3-minimum recipe).
// ---------------------------------------------------------------------------
__global__ __launch_bounds__(256) void moe_gemm(
    const unsigned short* __restrict__ xb, const unsigned short* __restrict__ wt,
    const int* __restrict__ counts, const int* __restrict__ lists,
    const float* __restrict__ wts, float* __restrict__ out,
    float* __restrict__ ybuf, int mode)
{
  const int e   = blockIdx.z;
  const int cnt = counts[e];
  const int m0  = blockIdx.y * 128;
  if (m0 >= cnt) return;
  const int n0  = blockIdx.x * 128;

  __shared__ unsigned short As[2][128 * 64];
  __shared__ unsigned short Bs[2][128 * 64];
  __shared__ int   rid[128];
  __shared__ float rw[128];

  const int t    = threadIdx.x;
  const int w    = t >> 6;
  const int lane = t & 63;

  if (t < 128) {
    const int r  = m0 + t;
    const int cr = (r < cnt) ? r : (cnt - 1);
    const int sid = lists[e * TOKENS + cr];
    rid[t] = sid;
    rw[t]  = (r < cnt) ? wts[sid] : 0.0f;
  }
  __syncthreads();

  // staging: lane = sub*8 + c; dest chunk c of row (i*32+w*8+sub);
  // source = logical chunk (c ^ sub)
  const int sub  = lane >> 3;
  const int csw  = ((lane & 7) ^ sub) * 8;   // swizzled source element offset
  const unsigned short* aSrc[4];
  const unsigned short* bSrc[4];
#pragma unroll
  for (int i = 0; i < 4; ++i) {
    const int rr = i * 32 + w * 8 + sub;
    aSrc[i] = xb + (size_t)(rid[rr] >> 1) * HDIM + csw;
    bSrc[i] = wt + ((size_t)e * ODIM + n0 + rr) * HDIM + csw;
  }

  floatx4 acc[4][4];
#pragma unroll
  for (int i = 0; i < 4; ++i)
#pragma unroll
    for (int j = 0; j < 4; ++j)
      acc[i][j] = (floatx4){0.f, 0.f, 0.f, 0.f};

  const int wm   = (w >> 1) * 64;
  const int wn   = (w & 1) * 64;
  const int frow = lane & 15;
  const int fk   = lane >> 4;        // k-chunk group 0..3
  const int rsw  = frow & 7;         // row swizzle key for fragment reads

  // prologue: stage tile 0 into buffer 0, drain, barrier
#pragma unroll
  for (int i = 0; i < 4; ++i) {
    async_ld16(aSrc[i], As[0] + (i * 32 + w * 8) * 64);
    async_ld16(bSrc[i], Bs[0] + (i * 32 + w * 8) * 64);
    aSrc[i] += 64; bSrc[i] += 64;
  }
  __syncthreads();

  int cur = 0;
  for (int kt = 0; kt < HDIM / 64; ++kt) {
    const int nxt = cur ^ 1;
    // phase A: issue next tile's staging loads (no wait) into the other buffer
    if (kt + 1 < HDIM / 64) {
#pragma unroll
      for (int i = 0; i < 4; ++i) {
        async_ld16(aSrc[i], As[nxt] + (i * 32 + w * 8) * 64);
        async_ld16(bSrc[i], Bs[nxt] + (i * 32 + w * 8) * 64);
        aSrc[i] += 64; bSrc[i] += 64;
      }
    }
    // phase B: compute current tile from As[cur]/Bs[cur]
#pragma unroll
    for (int kk = 0; kk < 2; ++kk) {
      short8 af[4], bfr[4];
#pragma unroll
      for (int mt = 0; mt < 4; ++mt)
        af[mt] = *(const short8*)(As[cur] + (wm + mt * 16 + frow) * 64 +
                                  (((kk * 4 + fk) ^ rsw) * 8));
#pragma unroll
      for (int nt = 0; nt < 4; ++nt)
        bfr[nt] = *(const short8*)(Bs[cur] + (wn + nt * 16 + frow) * 64 +
                                   (((kk * 4 + fk) ^ rsw) * 8));
#pragma unroll
      for (int mt = 0; mt < 4; ++mt)
#pragma unroll
        for (int nt = 0; nt < 4; ++nt)
          acc[mt][nt] = __builtin_amdgcn_mfma_f32_16x16x32_bf16(af[mt], bfr[nt], acc[mt][nt], 0, 0, 0);
    }
    // single drain+barrier per tile: waits vmcnt(0) for the loads issued at
    // the top of THIS iteration (they had the whole MFMA phase in flight)
    // and lgkmcnt(0) for all ds_reads of As[cur] before it gets overwritten.
    __syncthreads();
    cur = nxt;
  }

  // epilogue: C/D layout col=lane&15, row=(lane>>4)*4+reg
#pragma unroll
  for (int mt = 0; mt < 4; ++mt) {
    const int lrb = wm + mt * 16 + (lane >> 4) * 4;
#pragma unroll
    for (int r = 0; r < 4; ++r) {
      const int lr = lrb + r;
      if (m0 + lr < cnt) {
        const float wgt = rw[lr];
        if (mode) {
          float* ob = ybuf + (size_t)rid[lr] * ODIM + n0 + wn + (lane & 15);
#pragma unroll
          for (int nt = 0; nt < 4; ++nt)
            ob[nt * 16] = wgt * acc[mt][nt][r];
        } else {
          float* ob = out + (size_t)(rid[lr] >> 1) * ODIM + n0 + wn + (lane & 15);
#pragma unroll
          for (int nt = 0; nt < 4; ++nt)
            atomicAdd(ob + nt * 16, wgt * acc[mt][nt][r]);
        }
      }
    }
  }
}

// ---------------------------------------------------------------------------
// Kernel 4: combine — out[t] = ybuf[2t] + ybuf[2t+1]
// ---------------------------------------------------------------------------
__global__ __launch_bounds__(256) void combine_kernel(
    const float* __restrict__ ybuf, float* __restrict__ out)
{
  const int b = blockIdx.x;
  const int t = threadIdx.x;
  const float4* y0 = (const float4*)(ybuf + (size_t)(2 * b) * ODIM);
  const float4* y1 = (const float4*)(ybuf + (size_t)(2 * b + 1) * ODIM);
  float4* o = (float4*)(out + (size_t)b * ODIM);
#pragma unroll
  for (int i = 0; i < 4; ++i) {
    const int idx = i * 256 + t;
    const float4 a = y0[idx];
    const float4 c = y1[idx];
    o[idx] = make_float4(a.x + c.x, a.y + c.y, a.z + c.z, a.w + c.w);
  }
}

// ---------------------------------------------------------------------------
extern "C" void kernel_launch(void* const* d_in, const int* in_sizes, int n_in,
                              void* d_out, int out_size, void* d_ws, size_t ws_size,
                              hipStream_t stream) {
  const float* x  = (const float*)d_in[0];
  const float* gw = (const float*)d_in[1];
  const float* ew = (const float*)d_in[2];
  float* out = (float*)d_out;

  char* ws = (char*)d_ws;
  unsigned short* wt = (unsigned short*)ws;                        // 256 MiB bf16 W^T
  size_t off = (size_t)NEXP * HDIM * ODIM * 2;
  unsigned short* xb = (unsigned short*)(ws + off);                // 64 MiB bf16 x
  off += (size_t)TOKENS * HDIM * 2;
  int*   counts = (int*)(ws + off); off += 128;
  int*   lists  = (int*)(ws + off); off += (size_t)NEXP * TOKENS * sizeof(int);
  float* wts    = (float*)(ws + off); off += (size_t)TOKENS * 2 * sizeof(float);
  off = (off + 255) & ~(size_t)255;
  float* ybuf   = (float*)(ws + off);                              // 256 MiB fp32 slots
  const size_t need = off + (size_t)TOKENS * 2 * ODIM * sizeof(float);
  const int fast = (ws_size >= need) ? 1 : 0;
  (void)in_sizes; (void)n_in;

  hipMemsetAsync(counts, 0, 128, stream);
  if (!fast)
    hipMemsetAsync(d_out, 0, (size_t)out_size * sizeof(float), stream);

  gate_kernel<<<TOKENS, 256, 0, stream>>>(x, gw, xb, counts, lists, wts);
  wt_kernel<<<dim3(ODIM / 64, HDIM / 64, NEXP), 256, 0, stream>>>(ew, wt);
  moe_gemm<<<dim3(ODIM / 128, TOKENS / 128, NEXP), 256, 0, stream>>>(
      xb, wt, counts, lists, wts, out, ybuf, fast);
  if (fast)
    combine_kernel<<<TOKENS, 256, 0, stream>>>(ybuf, out);
}

// Round 5
// 1720.202 us; speedup vs baseline: 1.0945x; 1.0945x over previous
//
#include <hip/hip_runtime.h>
#include <cstdint>
#include <cstddef>

#define TOKENS 8192
#define HDIM 4096
#define ODIM 4096
#define NEXP 8

using short8  = __attribute__((ext_vector_type(8))) short;
using floatx4 = __attribute__((ext_vector_type(4))) float;

// fp32 -> bf16 with round-to-nearest-even
__device__ __forceinline__ unsigned short f2bf(float f) {
  unsigned u = __float_as_uint(f);
  u = u + 0x7fffu + ((u >> 16) & 1u);
  return (unsigned short)(u >> 16);
}

// async global->LDS, 16B per lane; LDS dest = wave-uniform base + lane*16
__device__ __forceinline__ void async_ld16(const void* g, void* l) {
  __builtin_amdgcn_global_load_lds((const __attribute__((address_space(1))) void*)g,
                                   (__attribute__((address_space(3))) void*)l,
                                   16, 0, 0);
}

// counted vmcnt waits (memory clobber: no VMEM/LDS op may cross)
__device__ __forceinline__ void wait_vm8() { asm volatile("s_waitcnt vmcnt(8)" ::: "memory"); }
__device__ __forceinline__ void wait_vm0() { asm volatile("s_waitcnt vmcnt(0)" ::: "memory"); }

// ---------------------------------------------------------------------------
// Kernel 1: gating (fp64 logits -> top-2 -> softmax) + x fp32->bf16.
// Slot scheme: sid = 2*token + k (k=0 top expert, k=1 second expert).
// ---------------------------------------------------------------------------
__global__ __launch_bounds__(256) void gate_kernel(
    const float* __restrict__ x, const float* __restrict__ gw,
    unsigned short* __restrict__ xb, int* __restrict__ counts,
    int* __restrict__ lists, float* __restrict__ wts)
{
  const int b = blockIdx.x;
  const int t = threadIdx.x;
  const float4* xr = (const float4*)(x + (size_t)b * HDIM);

  double acc[NEXP];
#pragma unroll
  for (int e = 0; e < NEXP; ++e) acc[e] = 0.0;

#pragma unroll
  for (int i = 0; i < 4; ++i) {
    const int idx = i * 256 + t;
    const float4 v = xr[idx];
    ushort4 pack = make_ushort4(f2bf(v.x), f2bf(v.y), f2bf(v.z), f2bf(v.w));
    *(ushort4*)(xb + (size_t)b * HDIM + (size_t)idx * 4) = pack;
    const float* g = gw + (size_t)idx * 4 * NEXP;
    const float xs[4] = {v.x, v.y, v.z, v.w};
#pragma unroll
    for (int j = 0; j < 4; ++j) {
      const float4 g0 = *(const float4*)(g + j * NEXP);
      const float4 g1 = *(const float4*)(g + j * NEXP + 4);
      const double xv = (double)xs[j];
      acc[0] += xv * (double)g0.x; acc[1] += xv * (double)g0.y;
      acc[2] += xv * (double)g0.z; acc[3] += xv * (double)g0.w;
      acc[4] += xv * (double)g1.x; acc[5] += xv * (double)g1.y;
      acc[6] += xv * (double)g1.z; acc[7] += xv * (double)g1.w;
    }
  }

#pragma unroll
  for (int off = 32; off > 0; off >>= 1)
#pragma unroll
    for (int e = 0; e < NEXP; ++e)
      acc[e] += __shfl_down(acc[e], off);

  __shared__ double sred[4][NEXP];
  const int w = t >> 6, lane = t & 63;
  if (lane == 0)
#pragma unroll
    for (int e = 0; e < NEXP; ++e) sred[w][e] = acc[e];
  __syncthreads();

  if (t == 0) {
    double lg[NEXP];
#pragma unroll
    for (int e = 0; e < NEXP; ++e)
      lg[e] = sred[0][e] + sred[1][e] + sred[2][e] + sred[3][e];
    int i0 = 0; double v0 = lg[0];
    for (int e = 1; e < NEXP; ++e) if (lg[e] > v0) { v0 = lg[e]; i0 = e; }
    int i1 = -1; double v1 = -1e300;
    for (int e = 0; e < NEXP; ++e) if (e != i0 && lg[e] > v1) { v1 = lg[e]; i1 = e; }
    const double d = exp(v1 - v0);
    const float w0 = (float)(1.0 / (1.0 + d));
    const float w1 = (float)(d / (1.0 + d));
    wts[2 * b]     = w0;
    wts[2 * b + 1] = w1;
    int p0 = atomicAdd(&counts[i0], 1);
    lists[i0 * TOKENS + p0] = 2 * b;
    int p1 = atomicAdd(&counts[i1], 1);
    lists[i1 * TOKENS + p1] = 2 * b + 1;
  }
}

// ---------------------------------------------------------------------------
// Kernel 2: expert_w fp32 [E,H,O] -> bf16 transposed [E,O,H]  (B^T for MFMA)
// ---------------------------------------------------------------------------
__global__ __launch_bounds__(256) void wt_kernel(
    const float* __restrict__ W, unsigned short* __restrict__ wt)
{
  const int e  = blockIdx.z;
  const int h0 = blockIdx.y * 64;
  const int o0 = blockIdx.x * 64;
  const int t  = threadIdx.x;
  __shared__ unsigned T[64 * 33];

  const float* Wb = W + (size_t)e * HDIM * ODIM;
  const int rp = t >> 4;       // 0..15  (h-pair)
  const int cq = t & 15;       // o-quad
#pragma unroll
  for (int p = 0; p < 2; ++p) {
    const int h = 2 * rp + 32 * p;
    const float4 v0 = *(const float4*)(Wb + (size_t)(h0 + h) * ODIM + o0 + 4 * cq);
    const float4 v1 = *(const float4*)(Wb + (size_t)(h0 + h + 1) * ODIM + o0 + 4 * cq);
    const float a0[4] = {v0.x, v0.y, v0.z, v0.w};
    const float a1[4] = {v1.x, v1.y, v1.z, v1.w};
#pragma unroll
    for (int j = 0; j < 4; ++j) {
      unsigned d = (unsigned)f2bf(a0[j]) | ((unsigned)f2bf(a1[j]) << 16);
      T[(4 * cq + j) * 33 + (h >> 1)] = d;
    }
  }
  __syncthreads();

#pragma unroll
  for (int p = 0; p < 2; ++p) {
    const int o_l = p * 32 + (t >> 3);
    const int dw  = (t & 7) * 4;
    const unsigned d0 = T[o_l * 33 + dw];
    const unsigned d1 = T[o_l * 33 + dw + 1];
    const unsigned d2 = T[o_l * 33 + dw + 2];
    const unsigned d3 = T[o_l * 33 + dw + 3];
    uint4 pack = make_uint4(d0, d1, d2, d3);
    *(uint4*)(wt + ((size_t)e * ODIM + o0 + o_l) * HDIM + h0 + dw * 2) = pack;
  }
}

// ---------------------------------------------------------------------------
// Kernel 3: grouped gather-GEMM, XOR-swizzled LDS, counted-vmcnt pipeline
// (T3+T4): per K-tile  STAGE(next buf) -> vmcnt(8) -> s_barrier -> ds_read+
// MFMA(cur buf) -> s_barrier.  vmcnt never drains to 0 in the main loop;
// buffers are statically named (no runtime-indexed LDS addressing).
// Race analysis: RAW (stage->read): each wave waits its own vmcnt for the
// cur-buf loads, then barrier-1 => all waves' cur-buf stages landed.
// WAR (read->re-stage): barrier-2 after compute => no wave stages into a
// buffer while any wave still reads it (buffer re-staged only next tile).
// ---------------------------------------------------------------------------
__global__ __launch_bounds__(256) void moe_gemm(
    const unsigned short* __restrict__ xb, const unsigned short* __restrict__ wt,
    const int* __restrict__ counts, const int* __restrict__ lists,
    const float* __restrict__ wts, float* __restrict__ out,
    float* __restrict__ ybuf, int mode)
{
  const int e   = blockIdx.z;
  const int cnt = counts[e];
  const int m0  = blockIdx.y * 128;
  if (m0 >= cnt) return;
  const int n0  = blockIdx.x * 128;

  __shared__ unsigned short As0[128 * 64];
  __shared__ unsigned short As1[128 * 64];
  __shared__ unsigned short Bs0[128 * 64];
  __shared__ unsigned short Bs1[128 * 64];
  __shared__ int   rid[128];
  __shared__ float rw[128];

  const int t    = threadIdx.x;
  const int w    = t >> 6;
  const int lane = t & 63;

  if (t < 128) {
    const int r  = m0 + t;
    const int cr = (r < cnt) ? r : (cnt - 1);
    const int sid = lists[e * TOKENS + cr];
    rid[t] = sid;
    rw[t]  = (r < cnt) ? wts[sid] : 0.0f;
  }
  __syncthreads();

  // staging: lane = sub*8 + c; dest chunk c of row (i*32+w*8+sub);
  // source = logical chunk (c ^ sub)
  const int sub  = lane >> 3;
  const int csw  = ((lane & 7) ^ sub) * 8;   // swizzled source element offset
  const unsigned short* aSrc[4];
  const unsigned short* bSrc[4];
#pragma unroll
  for (int i = 0; i < 4; ++i) {
    const int rr = i * 32 + w * 8 + sub;
    aSrc[i] = xb + (size_t)(rid[rr] >> 1) * HDIM + csw;
    bSrc[i] = wt + ((size_t)e * ODIM + n0 + rr) * HDIM + csw;
  }

  floatx4 acc[4][4];
#pragma unroll
  for (int i = 0; i < 4; ++i)
#pragma unroll
    for (int j = 0; j < 4; ++j)
      acc[i][j] = (floatx4){0.f, 0.f, 0.f, 0.f};

  const int wm   = (w >> 1) * 64;
  const int wn   = (w & 1) * 64;
  const int frow = lane & 15;
  const int fk   = lane >> 4;        // k-chunk group 0..3
  const int rsw  = frow & 7;         // row swizzle key for fragment reads

  auto STAGE = [&](unsigned short* A, unsigned short* B) {
#pragma unroll
    for (int i = 0; i < 4; ++i) {
      async_ld16(aSrc[i], A + (i * 32 + w * 8) * 64);
      async_ld16(bSrc[i], B + (i * 32 + w * 8) * 64);
      aSrc[i] += 64; bSrc[i] += 64;
    }
  };

  auto COMPUTE = [&](const unsigned short* A, const unsigned short* B) {
#pragma unroll
    for (int kk = 0; kk < 2; ++kk) {
      short8 af[4], bfr[4];
#pragma unroll
      for (int mt = 0; mt < 4; ++mt)
        af[mt] = *(const short8*)(A + (wm + mt * 16 + frow) * 64 +
                                  (((kk * 4 + fk) ^ rsw) * 8));
#pragma unroll
      for (int nt = 0; nt < 4; ++nt)
        bfr[nt] = *(const short8*)(B + (wn + nt * 16 + frow) * 64 +
                                   (((kk * 4 + fk) ^ rsw) * 8));
#pragma unroll
      for (int mt = 0; mt < 4; ++mt)
#pragma unroll
        for (int nt = 0; nt < 4; ++nt)
          acc[mt][nt] = __builtin_amdgcn_mfma_f32_16x16x32_bf16(af[mt], bfr[nt], acc[mt][nt], 0, 0, 0);
    }
  };

  // prologue: stage K-tile 0 into buf0 (8 loads in flight)
  STAGE(As0, Bs0);

  // main loop: 63 staged tiles (kt = 0..62), unrolled x2 for static buffers
#pragma unroll 1
  for (int kt2 = 0; kt2 < 31; ++kt2) {
    // even tile: compute buf0, stage buf1
    STAGE(As1, Bs1);
    wait_vm8();                              // buf0 loads landed (ours)
    __builtin_amdgcn_s_barrier();            // everyone's buf0 loads landed
    __builtin_amdgcn_sched_barrier(0);
    COMPUTE(As0, Bs0);
    __builtin_amdgcn_sched_barrier(0);
    __builtin_amdgcn_s_barrier();            // all reads of buf0 done
    // odd tile: compute buf1, stage buf0
    STAGE(As0, Bs0);
    wait_vm8();
    __builtin_amdgcn_s_barrier();
    __builtin_amdgcn_sched_barrier(0);
    COMPUTE(As1, Bs1);
    __builtin_amdgcn_sched_barrier(0);
    __builtin_amdgcn_s_barrier();
  }
  // kt = 62: compute buf0, stage buf1 (last stage, for kt=63)
  STAGE(As1, Bs1);
  wait_vm8();
  __builtin_amdgcn_s_barrier();
  __builtin_amdgcn_sched_barrier(0);
  COMPUTE(As0, Bs0);
  __builtin_amdgcn_sched_barrier(0);
  __builtin_amdgcn_s_barrier();
  // kt = 63: final tile, no further staging
  wait_vm0();
  __builtin_amdgcn_s_barrier();
  __builtin_amdgcn_sched_barrier(0);
  COMPUTE(As1, Bs1);

  // epilogue: C/D layout col=lane&15, row=(lane>>4)*4+reg
#pragma unroll
  for (int mt = 0; mt < 4; ++mt) {
    const int lrb = wm + mt * 16 + (lane >> 4) * 4;
#pragma unroll
    for (int r = 0; r < 4; ++r) {
      const int lr = lrb + r;
      if (m0 + lr < cnt) {
        const float wgt = rw[lr];
        if (mode) {
          float* ob = ybuf + (size_t)rid[lr] * ODIM + n0 + wn + (lane & 15);
#pragma unroll
          for (int nt = 0; nt < 4; ++nt)
            ob[nt * 16] = wgt * acc[mt][nt][r];
        } else {
          float* ob = out + (size_t)(rid[lr] >> 1) * ODIM + n0 + wn + (lane & 15);
#pragma unroll
          for (int nt = 0; nt < 4; ++nt)
            atomicAdd(ob + nt * 16, wgt * acc[mt][nt][r]);
        }
      }
    }
  }
}

// ---------------------------------------------------------------------------
// Kernel 4: combine — out[t] = ybuf[2t] + ybuf[2t+1]
// ---------------------------------------------------------------------------
__global__ __launch_bounds__(256) void combine_kernel(
    const float* __restrict__ ybuf, float* __restrict__ out)
{
  const int b = blockIdx.x;
  const int t = threadIdx.x;
  const float4* y0 = (const float4*)(ybuf + (size_t)(2 * b) * ODIM);
  const float4* y1 = (const float4*)(ybuf + (size_t)(2 * b + 1) * ODIM);
  float4* o = (float4*)(out + (size_t)b * ODIM);
#pragma unroll
  for (int i = 0; i < 4; ++i) {
    const int idx = i * 256 + t;
    const float4 a = y0[idx];
    const float4 c = y1[idx];
    o[idx] = make_float4(a.x + c.x, a.y + c.y, a.z + c.z, a.w + c.w);
  }
}

// ---------------------------------------------------------------------------
extern "C" void kernel_launch(void* const* d_in, const int* in_sizes, int n_in,
                              void* d_out, int out_size, void* d_ws, size_t ws_size,
                              hipStream_t stream) {
  const float* x  = (const float*)d_in[0];
  const float* gw = (const float*)d_in[1];
  const float* ew = (const float*)d_in[2];
  float* out = (float*)d_out;

  char* ws = (char*)d_ws;
  unsigned short* wt = (unsigned short*)ws;                        // 256 MiB bf16 W^T
  size_t off = (size_t)NEXP * HDIM * ODIM * 2;
  unsigned short* xb = (unsigned short*)(ws + off);                // 64 MiB bf16 x
  off += (size_t)TOKENS * HDIM * 2;
  int*   counts = (int*)(ws + off); off += 128;
  int*   lists  = (int*)(ws + off); off += (size_t)NEXP * TOKENS * sizeof(int);
  float* wts    = (float*)(ws + off); off += (size_t)TOKENS * 2 * sizeof(float);
  off = (off + 255) & ~(size_t)255;
  float* ybuf   = (float*)(ws + off);                              // 256 MiB fp32 slots
  const size_t need = off + (size_t)TOKENS * 2 * ODIM * sizeof(float);
  const int fast = (ws_size >= need) ? 1 : 0;
  (void)in_sizes; (void)n_in;

  hipMemsetAsync(counts, 0, 128, stream);
  if (!fast)
    hipMemsetAsync(d_out, 0, (size_t)out_size * sizeof(float), stream);

  gate_kernel<<<TOKENS, 256, 0, stream>>>(x, gw, xb, counts, lists, wts);
  wt_kernel<<<dim3(ODIM / 64, HDIM / 64, NEXP), 256, 0, stream>>>(ew, wt);
  moe_gemm<<<dim3(ODIM / 128, TOKENS / 128, NEXP), 256, 0, stream>>>(
      xb, wt, counts, lists, wts, out, ybuf, fast);
  if (fast)
    combine_kernel<<<TOKENS, 256, 0, stream>>>(ybuf, out);
}